// Round 5
// baseline (164.472 us; speedup 1.0000x reference)
//
#include <hip/hip_runtime.h>

// Problem constants (B,N,D,U) = (8,2048,512,128)
#define BB 8
#define NN 2048
#define DD 512
#define UU 128
#define SPLITS 8
#define KSPLIT 256   // keys per split
#define TK 32        // keys per attn inner tile (double-buffered)

typedef __bf16 bf16_t;
typedef __bf16 bf16x4 __attribute__((ext_vector_type(4)));
typedef __bf16 bf16x8 __attribute__((ext_vector_type(8)));
typedef float floatx4 __attribute__((ext_vector_type(4)));

__device__ __forceinline__ floatx4 mfma16(bf16x8 a, bf16x8 b, floatx4 c) {
  return __builtin_amdgcn_mfma_f32_16x16x32_bf16(a, b, c, 0, 0, 0);
}

// XOR swizzle on 16B granules (3-bit, within 8-granule groups)
#define SW(r, g) ((((g) ^ ((r) & 7)) * 8))

// async 16B global->LDS copy (dest = wave-uniform base + lane*16)
__device__ __forceinline__ void gld_lds16(const bf16_t* g, bf16_t* l) {
  __builtin_amdgcn_global_load_lds(
      (const __attribute__((address_space(1))) unsigned int*)g,
      (__attribute__((address_space(3))) unsigned int*)l, 16, 0, 0);
}

// ---------------------------------------------------------------------------
// Kernel 1: cast X (fp32) -> bf16, granule-swizzled (3-bit XOR within 64-col chunks)
// ---------------------------------------------------------------------------
__global__ __launch_bounds__(256) void cast_x_kernel(const float* __restrict__ x,
                                                     bf16_t* __restrict__ xb) {
  int G = blockIdx.x * 256 + threadIdx.x;   // granule id (8 elems)
  int token = G >> 6;
  int g = G & 63;
  int dstg = (g & 56) | ((g & 7) ^ (token & 7));
  const float4* src = reinterpret_cast<const float4*>(x) + (size_t)G * 2;
  float4 a = src[0], b = src[1];
  bf16x8 o;
  o[0] = (bf16_t)a.x; o[1] = (bf16_t)a.y; o[2] = (bf16_t)a.z; o[3] = (bf16_t)a.w;
  o[4] = (bf16_t)b.x; o[5] = (bf16_t)b.y; o[6] = (bf16_t)b.z; o[7] = (bf16_t)b.w;
  *reinterpret_cast<bf16x8*>(&xb[(size_t)token * 512 + dstg * 8]) = o;
}

// ---------------------------------------------------------------------------
// Kernel 2: pack weights transposed bf16, granule-swizzled (3-bit XOR)
// ---------------------------------------------------------------------------
__global__ __launch_bounds__(256) void pack_w_kernel(const float* __restrict__ wq,
                                                     const float* __restrict__ wk,
                                                     const float* __restrict__ wv,
                                                     const float* __restrict__ wo,
                                                     bf16_t* __restrict__ wqkvt,
                                                     bf16_t* __restrict__ wot) {
  int gid = blockIdx.x * 256 + threadIdx.x;
  if (gid < 384 * 512) {
    int nrow = gid >> 9;
    int kdst = gid & 511;
    int ksrc = (kdst & ~56) | (((((kdst >> 3) & 7)) ^ (nrow & 7)) << 3);
    const float* src = (nrow < 128) ? wq : ((nrow < 256) ? wk : wv);
    int n = nrow & 127;
    wqkvt[gid] = (bf16_t)src[ksrc * 128 + n];
  } else {
    int g = gid - 384 * 512;
    int nrow = g >> 7;
    int kdst = g & 127;
    int ksrc = (kdst & ~56) | (((((kdst >> 3) & 7)) ^ (nrow & 7)) << 3);
    wot[g] = (bf16_t)wo[ksrc * 512 + nrow];
  }
}

// ---------------------------------------------------------------------------
// Kernel 3: QKV GEMM, m97-style 128x128 tile, 4 waves (64x64 each), BK=64.
// Writes Q unswizzled; K 3-bit-swizzled; Vt 2-bit-swizzled (within-32-key).
// ---------------------------------------------------------------------------
__global__ __launch_bounds__(256, 2) void qkv_gemm_kernel(const bf16_t* __restrict__ xb,
                                                          const bf16_t* __restrict__ wqkvt,
                                                          bf16_t* __restrict__ Q,
                                                          bf16_t* __restrict__ K,
                                                          bf16_t* __restrict__ Vt) {
  __shared__ bf16_t lA[128 * 64];
  __shared__ bf16_t lB[128 * 64];
  const int m0 = blockIdx.x * 128;
  const int n0 = blockIdx.y * 128;
  const int tid = threadIdx.x;
  const int w = tid >> 6, lane = tid & 63;
  const int quad = lane >> 4, l15 = lane & 15;
  const int mh = (w & 1) * 64, nh = (w >> 1) * 64;

  floatx4 zero4 = {0.f, 0.f, 0.f, 0.f};
  floatx4 acc[4][4];
#pragma unroll
  for (int mt = 0; mt < 4; mt++)
#pragma unroll
    for (int nt = 0; nt < 4; nt++) acc[mt][nt] = zero4;

  for (int kc = 0; kc < 512; kc += 64) {
    __syncthreads();
#pragma unroll
    for (int i = 0; i < 4; i++) {
      int G = tid + i * 256;
      int r = G >> 3, g = G & 7;
      gld_lds16(&xb[(size_t)(m0 + r) * 512 + kc + g * 8], &lA[G * 8]);
    }
#pragma unroll
    for (int i = 0; i < 4; i++) {
      int G = tid + i * 256;
      int r = G >> 3, g = G & 7;
      gld_lds16(&wqkvt[(size_t)(n0 + r) * 512 + kc + g * 8], &lB[G * 8]);
    }
    asm volatile("s_waitcnt vmcnt(0)" ::: "memory");
    __syncthreads();
#pragma unroll
    for (int kb = 0; kb < 2; kb++) {
      bf16x8 af[4], bfr[4];
#pragma unroll
      for (int mt = 0; mt < 4; mt++)
        af[mt] = *reinterpret_cast<const bf16x8*>(
            &lA[(mh + mt * 16 + l15) * 64 + SW(l15, kb * 4 + quad)]);
#pragma unroll
      for (int nt = 0; nt < 4; nt++)
        bfr[nt] = *reinterpret_cast<const bf16x8*>(
            &lB[(nh + nt * 16 + l15) * 64 + SW(l15, kb * 4 + quad)]);
#pragma unroll
      for (int mt = 0; mt < 4; mt++)
#pragma unroll
        for (int nt = 0; nt < 4; nt++)
          acc[mt][nt] = mfma16(af[mt], bfr[nt], acc[mt][nt]);
    }
  }

  // epilogue: C/D col = l15, row = quad*4+r
#pragma unroll
  for (int nt = 0; nt < 4; nt++) {
    int n = n0 + nh + nt * 16 + l15;
#pragma unroll
    for (int mt = 0; mt < 4; mt++) {
#pragma unroll
      for (int r = 0; r < 4; r++) {
        int token = m0 + mh + mt * 16 + quad * 4 + r;
        bf16_t h = (bf16_t)acc[mt][nt][r];
        if (n < 128) {
          Q[(size_t)token * 128 + n] = h;
        } else if (n < 256) {
          int nk = n - 128;
          int nsw = (nk & ~56) | ((((nk >> 3) & 7) ^ (token & 7)) << 3);
          K[(size_t)token * 128 + nsw] = h;
        } else {
          int bb = token >> 11;
          int t = token & 2047;
          int u = n - 256;
          int tsw = (t & ~24) | ((((t >> 3) & 3) ^ (u & 3)) << 3);
          Vt[((size_t)bb * 128 + u) * 2048 + tsw] = h;
        }
      }
    }
  }
}

// ---------------------------------------------------------------------------
// Kernel 4: split-K flash attention, no-max softmax, double-buffered 32-key
// tiles with partial vmcnt waits (prefetch stays in flight across barriers).
// Block: 128 queries x KSPLIT keys, 4 waves x 32 queries.
// LDS: lK 2x8K + lV 2x8K + lP 8K = 40K.
// ---------------------------------------------------------------------------
__global__ __launch_bounds__(256, 3) void attn_kernel(const bf16_t* __restrict__ Q,
                                                      const bf16_t* __restrict__ K,
                                                      const bf16_t* __restrict__ Vt,
                                                      bf16_t* __restrict__ Op,
                                                      float* __restrict__ ml) {
  __shared__ bf16_t lK[2][TK * 128];
  __shared__ bf16_t lV[2][128 * TK];
  __shared__ bf16_t lP[4][32 * TK];

  const int b = blockIdx.y;
  const int qb = blockIdx.x;
  const int s = blockIdx.z;
  const int tid = threadIdx.x;
  const int w = tid >> 6, lane = tid & 63;
  const int quad = lane >> 4, l15 = lane & 15;
  const float c = 0.08838834764831845f * 1.4426950408889634f;  // 1/sqrt(U)*log2e

  // Q fragments (B-operand of S^T): lane l15 = query-within-16
  bf16x8 qf[2][4];
#pragma unroll
  for (int mt = 0; mt < 2; mt++) {
    const bf16_t* qrow =
        &Q[((size_t)b * NN + qb * 128 + w * 32 + mt * 16 + l15) * 128 + quad * 8];
#pragma unroll
    for (int kb = 0; kb < 4; kb++)
      qf[mt][kb] = *reinterpret_cast<const bf16x8*>(qrow + kb * 32);
  }

  float l_part[2] = {0.f, 0.f};
  floatx4 zero4 = {0.f, 0.f, 0.f, 0.f};
  floatx4 accO[2][8];
#pragma unroll
  for (int mt = 0; mt < 2; mt++)
#pragma unroll
    for (int ut = 0; ut < 8; ut++) accO[mt][ut] = zero4;

  bf16_t* pw = &lP[w][0];
  const int kt0 = s * KSPLIT;
  const bf16_t* kbase = &K[((size_t)b * NN + kt0) * 128];
  const bf16_t* vbase = &Vt[(size_t)b * 128 * 2048 + kt0];

  // stage tile 0
  {
#pragma unroll
    for (int i = 0; i < 2; i++) {
      int G = tid + i * 256;
      gld_lds16(kbase + (size_t)G * 8, &lK[0][G * 8]);
    }
#pragma unroll
    for (int i = 0; i < 2; i++) {
      int G = tid + i * 256;
      gld_lds16(vbase + (size_t)(G >> 2) * 2048 + (G & 3) * 8, &lV[0][G * 8]);
    }
  }

  for (int it = 0; it < KSPLIT / TK; it++) {
    const int buf = it & 1;
    if (it < KSPLIT / TK - 1) {
      // prefetch next tile into the other buffer (4 gld/thread)
      const int nb = buf ^ 1;
      const bf16_t* ks = kbase + (size_t)(it + 1) * TK * 128;
      const bf16_t* vs = vbase + (it + 1) * TK;
#pragma unroll
      for (int i = 0; i < 2; i++) {
        int G = tid + i * 256;
        gld_lds16(ks + (size_t)G * 8, &lK[nb][G * 8]);
      }
#pragma unroll
      for (int i = 0; i < 2; i++) {
        int G = tid + i * 256;
        gld_lds16(vs + (size_t)(G >> 2) * 2048 + (G & 3) * 8, &lV[nb][G * 8]);
      }
      asm volatile("s_waitcnt vmcnt(4)" ::: "memory");  // current tile done
    } else {
      asm volatile("s_waitcnt vmcnt(0)" ::: "memory");
    }
    asm volatile("s_barrier" ::: "memory");

    // S^T[key][query] over 32 keys: accS[km][mt], km in {0,1}
    floatx4 accS[2][2];
#pragma unroll
    for (int km = 0; km < 2; km++)
#pragma unroll
      for (int mt = 0; mt < 2; mt++) accS[km][mt] = zero4;
#pragma unroll
    for (int kb = 0; kb < 4; kb++) {
#pragma unroll
      for (int km = 0; km < 2; km++) {
        int g = kb * 4 + quad;
        int gs = (g & 8) | ((g & 7) ^ (l15 & 7));
        bf16x8 kf = *reinterpret_cast<const bf16x8*>(
            &lK[buf][(km * 16 + l15) * 128 + gs * 8]);
#pragma unroll
        for (int mt = 0; mt < 2; mt++)
          accS[km][mt] = mfma16(kf, qf[mt][kb], accS[km][mt]);
      }
    }

    // p = exp2(c*s); accumulate l; pack P -> [q][key] LDS (b64, 2-bit swizzle)
#pragma unroll
    for (int km = 0; km < 2; km++) {
#pragma unroll
      for (int mt = 0; mt < 2; mt++) {
        float p0 = __builtin_amdgcn_exp2f(accS[km][mt][0] * c);
        float p1 = __builtin_amdgcn_exp2f(accS[km][mt][1] * c);
        float p2 = __builtin_amdgcn_exp2f(accS[km][mt][2] * c);
        float p3 = __builtin_amdgcn_exp2f(accS[km][mt][3] * c);
        l_part[mt] += (p0 + p1) + (p2 + p3);
        bf16x4 pk;
        pk[0] = (bf16_t)p0; pk[1] = (bf16_t)p1; pk[2] = (bf16_t)p2; pk[3] = (bf16_t)p3;
        int q = mt * 16 + l15;
        int gk = (km * 2 + (quad >> 1)) ^ (q & 3);
        *reinterpret_cast<bf16x4*>(&pw[q * TK + gk * 8 + (quad & 1) * 4]) = pk;
      }
    }
    asm volatile("s_waitcnt lgkmcnt(0)" ::: "memory");

    // O += P V over this 32-key slice (single kb)
    bf16x8 pa[2];
#pragma unroll
    for (int mt = 0; mt < 2; mt++)
      pa[mt] = *reinterpret_cast<const bf16x8*>(
          &pw[(mt * 16 + l15) * TK + (quad ^ (l15 & 3)) * 8]);
#pragma unroll
    for (int ut = 0; ut < 8; ut++) {
      bf16x8 bv = *reinterpret_cast<const bf16x8*>(
          &lV[buf][(ut * 16 + l15) * TK + (quad ^ (l15 & 3)) * 8]);
#pragma unroll
      for (int mt = 0; mt < 2; mt++)
        accO[mt][ut] = mfma16(pa[mt], bv, accO[mt][ut]);
    }
    asm volatile("s_barrier" ::: "memory");  // protect buf before next overwrite
  }

#pragma unroll
  for (int mt = 0; mt < 2; mt++) {
    float v = l_part[mt];
    v += __shfl_xor(v, 16);
    v += __shfl_xor(v, 32);
    l_part[mt] = v;
  }

  size_t base = ((size_t)(b * 16 + qb) * SPLITS + s);
  bf16_t* op = Op + base * (128 * 128);
  float* mlp = ml + base * 128;
#pragma unroll
  for (int mt = 0; mt < 2; mt++)
#pragma unroll
    for (int ut = 0; ut < 8; ut++)
#pragma unroll
      for (int r = 0; r < 4; r++)
        op[(w * 32 + mt * 16 + quad * 4 + r) * 128 + ut * 16 + l15] =
            (bf16_t)accO[mt][ut][r];
  if (quad == 0) {
#pragma unroll
    for (int mt = 0; mt < 2; mt++) mlp[w * 32 + mt * 16 + l15] = l_part[mt];
  }
}

// ---------------------------------------------------------------------------
// Kernel 4b: merge split-K partials -> ctx bf16, granule-swizzled (3-bit)
// ---------------------------------------------------------------------------
__global__ __launch_bounds__(256) void merge_kernel(const bf16_t* __restrict__ Op,
                                                    const float* __restrict__ ml,
                                                    bf16_t* __restrict__ ctx) {
  const int blk = blockIdx.x;                      // b*16 + qb
  const int q = threadIdx.x >> 1;                  // 0..127
  const int u0 = blockIdx.y * 64 + (threadIdx.x & 1) * 32;

  float L = 0.f;
  float o[32];
#pragma unroll
  for (int j = 0; j < 32; j++) o[j] = 0.f;
#pragma unroll
  for (int s = 0; s < SPLITS; s++) {
    L += ml[((size_t)blk * SPLITS + s) * 128 + q];
    const bf16_t* op = Op + ((size_t)blk * SPLITS + s) * 16384 + q * 128 + u0;
#pragma unroll
    for (int v = 0; v < 4; v++) {
      bf16x8 ch = *reinterpret_cast<const bf16x8*>(op + v * 8);
#pragma unroll
      for (int j = 0; j < 8; j++) o[v * 8 + j] += (float)ch[j];
    }
  }
  float inv = 1.0f / L;
  const int bb = blk >> 4, qbl = blk & 15;
  bf16_t* dst = ctx + ((size_t)bb * NN + qbl * 128 + q) * 128;
#pragma unroll
  for (int v = 0; v < 4; v++) {
    int g = (u0 >> 3) + v;
    int gsw = (g & 8) | ((g & 7) ^ (q & 7));
    bf16x8 ch;
#pragma unroll
    for (int j = 0; j < 8; j++) ch[j] = (bf16_t)(o[v * 8 + j] * inv);
    *reinterpret_cast<bf16x8*>(dst + gsw * 8) = ch;
  }
}

// ---------------------------------------------------------------------------
// Kernel 5: out = ctx @ W_o + b_o + X (HBM-bound: x0 + out traffic)
// ---------------------------------------------------------------------------
__global__ __launch_bounds__(256, 4) void out_gemm_kernel(const bf16_t* __restrict__ ctx,
                                                          const bf16_t* __restrict__ wot,
                                                          const float* __restrict__ bo,
                                                          const float* __restrict__ x0,
                                                          float* __restrict__ out) {
  __shared__ bf16_t lA[64 * 128];
  __shared__ bf16_t lB[64 * 128];
  const int m0 = blockIdx.x * 64;
  const int n0 = blockIdx.y * 64;
  const int tid = threadIdx.x;
  const int w = tid >> 6, lane = tid & 63;
  const int quad = lane >> 4, l15 = lane & 15;

#pragma unroll
  for (int i = 0; i < 4; i++) {
    int t = tid + i * 256;
    gld_lds16(&ctx[(size_t)m0 * 128 + t * 8], &lA[t * 8]);
    gld_lds16(&wot[(size_t)n0 * 128 + t * 8], &lB[t * 8]);
  }
  asm volatile("s_waitcnt vmcnt(0)" ::: "memory");
  __syncthreads();

  floatx4 zero4 = {0.f, 0.f, 0.f, 0.f};
  floatx4 acc[4];
#pragma unroll
  for (int nt = 0; nt < 4; nt++) acc[nt] = zero4;
#pragma unroll
  for (int kb = 0; kb < 4; kb++) {
    bf16x8 a = *reinterpret_cast<const bf16x8*>(&lA[(w * 16 + l15) * 128 + SW(l15, kb * 4 + quad)]);
#pragma unroll
    for (int nt = 0; nt < 4; nt++) {
      bf16x8 bfr = *reinterpret_cast<const bf16x8*>(&lB[(nt * 16 + l15) * 128 + SW(l15, kb * 4 + quad)]);
      acc[nt] = mfma16(a, bfr, acc[nt]);
    }
  }

#pragma unroll
  for (int nt = 0; nt < 4; nt++) {
    int n = n0 + nt * 16 + l15;
    float bias = bo[n];
#pragma unroll
    for (int r = 0; r < 4; r++) {
      size_t m = m0 + w * 16 + quad * 4 + r;
      out[m * 512 + n] = acc[nt][r] + bias + x0[m * 512 + n];
    }
  }
}

// ---------------------------------------------------------------------------
extern "C" void kernel_launch(void* const* d_in, const int* in_sizes, int n_in,
                              void* d_out, int out_size, void* d_ws, size_t ws_size,
                              hipStream_t stream) {
  const float* x  = (const float*)d_in[0];
  const float* wq = (const float*)d_in[1];
  const float* wk = (const float*)d_in[2];
  const float* wv = (const float*)d_in[3];
  const float* wo = (const float*)d_in[4];
  const float* bo = (const float*)d_in[5];
  float* out = (float*)d_out;

  char* ws = (char*)d_ws;
  // layout (bytes):
  //   0        Qb    4MB   (unswizzled)
  //   4M       Kb    4MB   (3-bit swizzled)
  //   8M       Vt    4MB   [8][128][2048] (2-bit swizzled)
  //   12M      Ctx   4MB   (3-bit swizzled)
  //   16M      Wqkvt 384KB (3-bit swizzled)
  //   16M+384K Wot   128KB (3-bit swizzled)
  //   16.5M    Xb    16MB  (3-bit swizzled; dead after qkv_gemm)
  //   16.5M    Op    32MB  [128 blk][8 split][128][128] bf16 (aliases Xb)
  //   48.5M    ml    512KB [128 blk][8 split][128] fp32
  bf16_t* Qb    = (bf16_t*)(ws);
  bf16_t* Kb    = (bf16_t*)(ws + 4194304);
  bf16_t* Vt    = (bf16_t*)(ws + 2 * 4194304);
  bf16_t* Ctx   = (bf16_t*)(ws + 3 * 4194304);
  bf16_t* Wqkvt = (bf16_t*)(ws + 4 * 4194304);
  bf16_t* Wot   = (bf16_t*)(ws + 4 * 4194304 + 393216);
  bf16_t* Xb    = (bf16_t*)(ws + 4 * 4194304 + 524288);
  bf16_t* Op    = (bf16_t*)(ws + 4 * 4194304 + 524288);   // aliases Xb
  float*  ml    = (float*)(ws + 4 * 4194304 + 524288 + 33554432);

  cast_x_kernel<<<4096, 256, 0, stream>>>(x, Xb);
  pack_w_kernel<<<1024, 256, 0, stream>>>(wq, wk, wv, wo, Wqkvt, Wot);
  qkv_gemm_kernel<<<dim3(128, 3), 256, 0, stream>>>(Xb, Wqkvt, Qb, Kb, Vt);
  attn_kernel<<<dim3(16, 8, SPLITS), 256, 0, stream>>>(Qb, Kb, Vt, Op, ml);
  merge_kernel<<<dim3(128, 2), 256, 0, stream>>>(Op, ml, Ctx);
  out_gemm_kernel<<<dim3(256, 8), 256, 0, stream>>>(Ctx, Wot, bo, x, out);
}